// Round 7
// baseline (2967.535 us; speedup 1.0000x reference)
//
#include <hip/hip_runtime.h>

#define BATCH 16
#define NP1 4096
#define NP2 2048
#define NP3 1024

typedef float v2f __attribute__((ext_vector_type(2)));

// IEEE ops that the compiler may NOT contract/reorder — used for every distance
// that feeds a discrete decision (kNN membership, FPS argmax). Order matches the
// reference: norms (x*x+y*y)+z*z ; knn d = (ni+nj) - 2*dot ; fps d = (dx^2+dy^2)+dz^2.
__device__ __forceinline__ float f_add(float a, float b) { return __fadd_rn(a, b); }
__device__ __forceinline__ float f_mul(float a, float b) { return __fmul_rn(a, b); }
__device__ __forceinline__ float f_sub(float a, float b) { return __fsub_rn(a, b); }
__device__ __forceinline__ float sqnorm3(float x, float y, float z) {
  return f_add(f_add(f_mul(x, x), f_mul(y, y)), f_mul(z, z));
}

__device__ __forceinline__ unsigned long long u64max(unsigned long long a,
                                                     unsigned long long b) {
  return a > b ? a : b;
}

template<int CTRL, int RMASK>
__device__ __forceinline__ unsigned long long dpp_u64(unsigned long long k) {
  const int lo = __builtin_amdgcn_update_dpp(0, (int)(unsigned)k, CTRL, RMASK, 0xF, true);
  const int hi = __builtin_amdgcn_update_dpp(0, (int)(unsigned)(k >> 32), CTRL, RMASK, 0xF, true);
  return ((unsigned long long)(unsigned)hi << 32) | (unsigned)lo;
}

// Wave64 max-reduce of the packed key; lane 63 ends with the full wave max.
__device__ __forceinline__ unsigned long long wave_max_key(unsigned long long k) {
  k = u64max(k, dpp_u64<0x111, 0xF>(k));
  k = u64max(k, dpp_u64<0x112, 0xF>(k));
  k = u64max(k, dpp_u64<0x114, 0xF>(k));
  k = u64max(k, dpp_u64<0x118, 0xF>(k));
  k = u64max(k, dpp_u64<0x142, 0xA>(k));
  k = u64max(k, dpp_u64<0x143, 0xC>(k));
  return k;
}

// ---------------- FPS device block: exact replica of the reference scan.
// 512 threads. Octant-sorted wave ranges with AABB cull. Cross-wave combine:
// per-wave slot writes (parity double-buffered) + broadcast tree read.
// NO GLOBAL MEMORY in the step loop: selected indices go to LDS (sampL);
// samp/pos_out are written once at the end. This keeps the per-step
// pre-barrier waitcnt lgkm-only (no vmcnt(0) store-drain on wave 0).
template<int N, int M>
__device__ void fps_block(char* __restrict__ smem, const float* __restrict__ P,
                          int* __restrict__ samp, float* __restrict__ pos_out)
{
#pragma clang fp contract(off)
  constexpr int THREADS = 512;
  constexpr int E = N / THREADS;
  constexpr int P2 = E / 2;
  float4* pos4 = (float4*)smem;                                   // [N] by orig idx
  unsigned short* ord = (unsigned short*)(smem + 16 * N);         // [N]
  int* sampL = (int*)(smem + 18 * N);                             // [M]
  unsigned* cursor = (unsigned*)(smem + 18 * N + 4 * M);          // [8]
  unsigned long long* slots =
      (unsigned long long*)(smem + 18 * N + 4 * M + 32);          // [2][8]
  const int tid = threadIdx.x;
  const int lane = tid & 63, wv = tid >> 6;
  if (tid < 8) cursor[tid] = 0u;
  __syncthreads();
  int oct[E];
#pragma unroll
  for (int e = 0; e < E; ++e) {
    const int t = e * THREADS + tid;
    const float x = P[t * 3], y = P[t * 3 + 1], z = P[t * 3 + 2];
    pos4[t] = make_float4(x, y, z, 0.f);
    oct[e] = (x > 0.5f ? 1 : 0) | (y > 0.5f ? 2 : 0) | (z > 0.5f ? 4 : 0);
    atomicAdd(&cursor[oct[e]], 1u);
  }
  __syncthreads();
  if (tid == 0) {
    unsigned run = 0;
#pragma unroll
    for (int o = 0; o < 8; ++o) { const unsigned c = cursor[o]; cursor[o] = run; run += c; }
  }
  __syncthreads();
#pragma unroll
  for (int e = 0; e < E; ++e) {
    const unsigned d = atomicAdd(&cursor[oct[e]], 1u);
    ord[d] = (unsigned short)(e * THREADS + tid);
  }
  __syncthreads();
  const float4 p0 = pos4[0];
  const float x0 = p0.x, y0 = p0.y, z0 = p0.z;
  v2f X2[P2], Y2[P2], Z2[P2], MD2[P2];
  unsigned ILO[E];
  unsigned long long key = 0;
  float mnx = 1e30f, mny = 1e30f, mnz = 1e30f;
  float mxx = -1e30f, mxy = -1e30f, mxz = -1e30f;
  {
    const v2f x0v = {x0, x0}, y0v = {y0, y0}, z0v = {z0, z0};
#pragma unroll
    for (int p = 0; p < P2; ++p) {
      const int q0 = wv * (64 * E) + (2 * p) * 64 + lane;  // wave-contiguous sorted range
      const int o0 = ord[q0], o1 = ord[q0 + 64];
      const float4 a0 = pos4[o0], a1 = pos4[o1];
      X2[p] = (v2f){a0.x, a1.x}; Y2[p] = (v2f){a0.y, a1.y}; Z2[p] = (v2f){a0.z, a1.z};
      mnx = fminf(mnx, fminf(a0.x, a1.x)); mxx = fmaxf(mxx, fmaxf(a0.x, a1.x));
      mny = fminf(mny, fminf(a0.y, a1.y)); mxy = fmaxf(mxy, fmaxf(a0.y, a1.y));
      mnz = fminf(mnz, fminf(a0.z, a1.z)); mxz = fmaxf(mxz, fmaxf(a0.z, a1.z));
      const v2f dx = X2[p] - x0v, dy = Y2[p] - y0v, dz = Z2[p] - z0v;
      MD2[p] = (dx * dx + dy * dy) + dz * dz;
      ILO[2 * p]     = 0xFFFFFFFFu - (unsigned)o0;
      ILO[2 * p + 1] = 0xFFFFFFFFu - (unsigned)o1;
      const unsigned long long k0 =
          ((unsigned long long)__float_as_uint(MD2[p].x) << 32) | ILO[2 * p];
      const unsigned long long k1 =
          ((unsigned long long)__float_as_uint(MD2[p].y) << 32) | ILO[2 * p + 1];
      key = u64max(key, u64max(k0, k1));
    }
  }
#pragma unroll
  for (int off = 1; off < 64; off <<= 1) {
    mnx = fminf(mnx, __shfl_xor(mnx, off)); mxx = fmaxf(mxx, __shfl_xor(mxx, off));
    mny = fminf(mny, __shfl_xor(mny, off)); mxy = fmaxf(mxy, __shfl_xor(mxy, off));
    mnz = fminf(mnz, __shfl_xor(mnz, off)); mxz = fmaxf(mxz, __shfl_xor(mxz, off));
  }
  if (tid == 0) sampL[0] = 0;
  bool dirty = true;
  unsigned long long wkey = 0;
#pragma unroll 1
  for (int s = 1; s < M; ++s) {
    if (dirty) wkey = wave_max_key(key);   // dirty is wave-uniform: full-exec DPP
    const int pb = s & 1;
    if (lane == 63) slots[pb * 8 + wv] = wkey;
    __syncthreads();
    unsigned long long v0 = slots[pb * 8 + 0], v1 = slots[pb * 8 + 1];
    unsigned long long v2 = slots[pb * 8 + 2], v3 = slots[pb * 8 + 3];
    unsigned long long v4 = slots[pb * 8 + 4], v5 = slots[pb * 8 + 5];
    unsigned long long v6 = slots[pb * 8 + 6], v7 = slots[pb * 8 + 7];
    v0 = u64max(v0, v1); v2 = u64max(v2, v3); v4 = u64max(v4, v5); v6 = u64max(v6, v7);
    v0 = u64max(v0, v2); v4 = u64max(v4, v6);
    v0 = u64max(v0, v4);
    const int gi = (int)(0xFFFFFFFFu - (unsigned)v0);
    const float4 sp = pos4[gi];
    if (tid == 0) sampL[s] = gi;          // LDS only — no vmcnt in the loop
    // wave-uniform cull: lower bound on any rn-computed d(i,sample) in this wave
    const float mdx = fmaxf(fmaxf(f_sub(mnx, sp.x), f_sub(sp.x, mxx)), 0.f);
    const float mdy = fmaxf(fmaxf(f_sub(mny, sp.y), f_sub(sp.y, mxy)), 0.f);
    const float mdz = fmaxf(fmaxf(f_sub(mnz, sp.z), f_sub(sp.z, mxz)), 0.f);
    const float mind2 = sqnorm3(mdx, mdy, mdz);
    const unsigned wmhi = (unsigned)__builtin_amdgcn_readlane((int)(unsigned)(wkey >> 32), 63);
    const float wmaxf = __uint_as_float(wmhi);
    if (mind2 < wmaxf) {
      dirty = true;
      key = 0;
      const v2f sxv = {sp.x, sp.x}, syv = {sp.y, sp.y}, szv = {sp.z, sp.z};
#pragma unroll
      for (int p = 0; p < P2; ++p) {
        const v2f dx = X2[p] - sxv, dy = Y2[p] - syv, dz = Z2[p] - szv;
        const v2f d = (dx * dx + dy * dy) + dz * dz;
        MD2[p] = __builtin_elementwise_min(MD2[p], d);
        const unsigned long long k0 =
            ((unsigned long long)__float_as_uint(MD2[p].x) << 32) | ILO[2 * p];
        const unsigned long long k1 =
            ((unsigned long long)__float_as_uint(MD2[p].y) << 32) | ILO[2 * p + 1];
        key = u64max(key, u64max(k0, k1));
      }
    } else {
      dirty = false;
    }
  }
  __syncthreads();
  // bulk copy-out: indices + gathered positions, once
  for (int s2 = tid; s2 < M; s2 += THREADS) {
    const int g = sampL[s2];
    samp[s2] = g;
    const float4 sp2 = pos4[g];
    pos_out[3 * s2 + 0] = sp2.x;
    pos_out[3 * s2 + 1] = sp2.y;
    pos_out[3 * s2 + 2] = sp2.z;
  }
}

__device__ __forceinline__ float f4c(const float4& v, int c) {
  return c == 0 ? v.x : c == 1 ? v.y : c == 2 ? v.z : v.w;
}
__device__ __forceinline__ void fma4(float4& a, float v, const float4& w) {
  a.x += v * w.x; a.y += v * w.y; a.z += v * w.z; a.w += v * w.w;
}

// ---------------- PointNet edge MLP (2C+3 -> 32 -> relu -> 32, max over K, relu)
template<int K, int C>
__device__ void pn_compute(
    const float4* __restrict__ sW1, const float4* __restrict__ sW2,
    const float* __restrict__ sb1, const float* __restrict__ sb2,
    const float* __restrict__ P, const float* __restrict__ Hsrc,
    const int* __restrict__ hmap, int i, float xi, float yi, float zi,
    const int* kn, float* __restrict__ outrow)
{
  float4 abase[8];
#pragma unroll
  for (int o = 0; o < 8; ++o)
    abase[o] = make_float4(sb1[4 * o], sb1[4 * o + 1], sb1[4 * o + 2], sb1[4 * o + 3]);
  if constexpr (C == 1) {
    const float v = Hsrc[hmap ? hmap[i] : i];
#pragma unroll
    for (int o = 0; o < 8; ++o) fma4(abase[o], v, sW1[o]);
  } else {
    const int ri = hmap ? hmap[i] : i;
    const float4* Hi = (const float4*)(Hsrc + (size_t)ri * C);
#pragma unroll
    for (int c4 = 0; c4 < C / 4; ++c4) {
      const float4 hv = Hi[c4];
#pragma unroll
      for (int q = 0; q < 4; ++q) {
        const float v = f4c(hv, q);
#pragma unroll
        for (int o = 0; o < 8; ++o) fma4(abase[o], v, sW1[(4 * c4 + q) * 8 + o]);
      }
    }
  }
  float4 best[8];
#pragma unroll
  for (int o = 0; o < 8; ++o)
    best[o] = make_float4(-__builtin_inff(), -__builtin_inff(), -__builtin_inff(), -__builtin_inff());

  auto edge_pair = [&](int j0, int j1) {
    float4 a0[8], a1[8];
#pragma unroll
    for (int o = 0; o < 8; ++o) { a0[o] = abase[o]; a1[o] = abase[o]; }
    const float rx0 = P[j0 * 3] - xi, ry0 = P[j0 * 3 + 1] - yi, rz0 = P[j0 * 3 + 2] - zi;
    const float rx1 = P[j1 * 3] - xi, ry1 = P[j1 * 3 + 1] - yi, rz1 = P[j1 * 3 + 2] - zi;
    if constexpr (C == 1) {
      const float v0 = Hsrc[hmap ? hmap[j0] : j0], v1 = Hsrc[hmap ? hmap[j1] : j1];
#pragma unroll
      for (int o = 0; o < 8; ++o) {
        const float4 w = sW1[C * 8 + o];
        fma4(a0[o], v0, w); fma4(a1[o], v1, w);
      }
    } else {
      const int r0i = hmap ? hmap[j0] : j0, r1i = hmap ? hmap[j1] : j1;
      const float4* Hj0 = (const float4*)(Hsrc + (size_t)r0i * C);
      const float4* Hj1 = (const float4*)(Hsrc + (size_t)r1i * C);
#pragma unroll
      for (int c4 = 0; c4 < C / 4; ++c4) {
        const float4 h0 = Hj0[c4], h1 = Hj1[c4];
#pragma unroll
        for (int q = 0; q < 4; ++q) {
          const float v0 = f4c(h0, q), v1 = f4c(h1, q);
#pragma unroll
          for (int o = 0; o < 8; ++o) {
            const float4 w = sW1[(C + 4 * c4 + q) * 8 + o];
            fma4(a0[o], v0, w); fma4(a1[o], v1, w);
          }
        }
      }
    }
    const float r0[3] = {rx0, ry0, rz0}, r1[3] = {rx1, ry1, rz1};
#pragma unroll
    for (int r = 0; r < 3; ++r) {
#pragma unroll
      for (int o = 0; o < 8; ++o) {
        const float4 w = sW1[(2 * C + r) * 8 + o];
        fma4(a0[o], r0[r], w); fma4(a1[o], r1[r], w);
      }
    }
#pragma unroll
    for (int o = 0; o < 8; ++o) {
      a0[o].x = fmaxf(a0[o].x, 0.f); a0[o].y = fmaxf(a0[o].y, 0.f);
      a0[o].z = fmaxf(a0[o].z, 0.f); a0[o].w = fmaxf(a0[o].w, 0.f);
      a1[o].x = fmaxf(a1[o].x, 0.f); a1[o].y = fmaxf(a1[o].y, 0.f);
      a1[o].z = fmaxf(a1[o].z, 0.f); a1[o].w = fmaxf(a1[o].w, 0.f);
    }
#pragma unroll
    for (int hf = 0; hf < 2; ++hf) {
      float4 m0[4], m1[4];
#pragma unroll
      for (int o4 = 0; o4 < 4; ++o4) {
        const int c0 = 16 * hf + 4 * o4;
        m0[o4] = make_float4(sb2[c0], sb2[c0 + 1], sb2[c0 + 2], sb2[c0 + 3]);
        m1[o4] = m0[o4];
      }
#pragma unroll
      for (int c = 0; c < 32; ++c) {
        const float v0 = f4c(a0[c >> 2], c & 3), v1 = f4c(a1[c >> 2], c & 3);
#pragma unroll
        for (int o4 = 0; o4 < 4; ++o4) {
          const float4 w = sW2[c * 8 + hf * 4 + o4];
          fma4(m0[o4], v0, w); fma4(m1[o4], v1, w);
        }
      }
#pragma unroll
      for (int o4 = 0; o4 < 4; ++o4) {
        float4& bb = best[hf * 4 + o4];
        bb.x = fmaxf(bb.x, fmaxf(m0[o4].x, m1[o4].x));
        bb.y = fmaxf(bb.y, fmaxf(m0[o4].y, m1[o4].y));
        bb.z = fmaxf(bb.z, fmaxf(m0[o4].z, m1[o4].z));
        bb.w = fmaxf(bb.w, fmaxf(m0[o4].w, m1[o4].w));
      }
    }
  };

  auto edge_single = [&](int j0) {
    float4 a0[8];
#pragma unroll
    for (int o = 0; o < 8; ++o) a0[o] = abase[o];
    const float rx0 = P[j0 * 3] - xi, ry0 = P[j0 * 3 + 1] - yi, rz0 = P[j0 * 3 + 2] - zi;
    if constexpr (C == 1) {
      const float v0 = Hsrc[hmap ? hmap[j0] : j0];
#pragma unroll
      for (int o = 0; o < 8; ++o) fma4(a0[o], v0, sW1[C * 8 + o]);
    } else {
      const int r0i = hmap ? hmap[j0] : j0;
      const float4* Hj0 = (const float4*)(Hsrc + (size_t)r0i * C);
#pragma unroll
      for (int c4 = 0; c4 < C / 4; ++c4) {
        const float4 h0 = Hj0[c4];
#pragma unroll
        for (int q = 0; q < 4; ++q) {
          const float v0 = f4c(h0, q);
#pragma unroll
          for (int o = 0; o < 8; ++o) fma4(a0[o], v0, sW1[(C + 4 * c4 + q) * 8 + o]);
        }
      }
    }
    const float r0[3] = {rx0, ry0, rz0};
#pragma unroll
    for (int r = 0; r < 3; ++r)
#pragma unroll
      for (int o = 0; o < 8; ++o) fma4(a0[o], r0[r], sW1[(2 * C + r) * 8 + o]);
#pragma unroll
    for (int o = 0; o < 8; ++o) {
      a0[o].x = fmaxf(a0[o].x, 0.f); a0[o].y = fmaxf(a0[o].y, 0.f);
      a0[o].z = fmaxf(a0[o].z, 0.f); a0[o].w = fmaxf(a0[o].w, 0.f);
    }
#pragma unroll
    for (int hf = 0; hf < 2; ++hf) {
      float4 m0[4];
#pragma unroll
      for (int o4 = 0; o4 < 4; ++o4) {
        const int c0 = 16 * hf + 4 * o4;
        m0[o4] = make_float4(sb2[c0], sb2[c0 + 1], sb2[c0 + 2], sb2[c0 + 3]);
      }
#pragma unroll
      for (int c = 0; c < 32; ++c) {
        const float v0 = f4c(a0[c >> 2], c & 3);
#pragma unroll
        for (int o4 = 0; o4 < 4; ++o4) fma4(m0[o4], v0, sW2[c * 8 + hf * 4 + o4]);
      }
#pragma unroll
      for (int o4 = 0; o4 < 4; ++o4) {
        float4& bb = best[hf * 4 + o4];
        bb.x = fmaxf(bb.x, m0[o4].x); bb.y = fmaxf(bb.y, m0[o4].y);
        bb.z = fmaxf(bb.z, m0[o4].z); bb.w = fmaxf(bb.w, m0[o4].w);
      }
    }
  };

#pragma unroll
  for (int e = 0; e + 1 < K; e += 2) edge_pair(kn[e], kn[e + 1]);
  if constexpr (K & 1) edge_single(kn[K - 1]);

  float4* ho = (float4*)outrow;
#pragma unroll
  for (int o = 0; o < 8; ++o)
    ho[o] = make_float4(fmaxf(best[o].x, 0.0f), fmaxf(best[o].y, 0.0f),
                        fmaxf(best[o].z, 0.0f), fmaxf(best[o].w, 0.0f));
}

// ---------------- fused kNN + PN layer for one query per thread (512-thr blocks).
template<int K, int NC, int C>
__device__ void fused_knn_pn(char* __restrict__ smem,
    const float* __restrict__ P, const float* __restrict__ Hsrc,
    const int* __restrict__ hmap,
    const float* __restrict__ W1, const float* __restrict__ b1,
    const float* __restrict__ W2, const float* __restrict__ b2,
    float* __restrict__ hout, int s)
{
  constexpr int CIN = 2 * C + 3;
  float4* tile = (float4*)smem;                       // [1024]
  float4* sW1 = (float4*)(smem + 16 * 1024);          // [CIN*8]
  float4* sW2 = sW1 + CIN * 8;                        // [32*8]
  float* sb1 = (float*)(sW2 + 32 * 8);
  float* sb2 = sb1 + 32;
  const int tid = threadIdx.x;
  for (int t = tid; t < CIN * 8; t += 512) sW1[t] = ((const float4*)W1)[t];
  for (int t = tid; t < 32 * 8; t += 512) sW2[t] = ((const float4*)W2)[t];
  if (tid < 32) { sb1[tid] = b1[tid]; sb2[tid] = b2[tid]; }

  const float xi = P[s * 3], yi = P[s * 3 + 1], zi = P[s * 3 + 2];
  const float ni = sqnorm3(xi, yi, zi);
  float bd[K]; int bj[K];
#pragma unroll
  for (int t = 0; t < K; ++t) { bd[t] = __builtin_inff(); bj[t] = 0; }
  for (int base = 0; base < NC; base += 1024) {
    __syncthreads();
    for (int t = tid; t < 1024; t += 512) {
      const float* q = P + (size_t)(base + t) * 3;
      const float x = q[0], y = q[1], z = q[2];
      tile[t] = make_float4(x, y, z, sqnorm3(x, y, z));
    }
    __syncthreads();
#pragma unroll 2
    for (int t = 0; t < 1024; ++t) {
      const float4 q = tile[t];
      const float dot = f_add(f_add(f_mul(xi, q.x), f_mul(yi, q.y)), f_mul(zi, q.z));
      const float d = f_sub(f_add(ni, q.w), f_mul(2.0f, dot));
      if (d < bd[K - 1]) {          // strict < keeps earlier index on ties
        bd[K - 1] = d; bj[K - 1] = base + t;
#pragma unroll
        for (int r = K - 1; r > 0; --r) {
          if (bd[r] < bd[r - 1]) {
            float td = bd[r]; bd[r] = bd[r - 1]; bd[r - 1] = td;
            int   tj = bj[r]; bj[r] = bj[r - 1]; bj[r - 1] = tj;
          } else break;
        }
      }
    }
  }
  pn_compute<K, C>(sW1, sW2, sb1, sb2, P, Hsrc, hmap, s, xi, yi, zi, bj,
                   hout + (size_t)s * 32);
}

// ---------------- mega-kernels: fps rides alongside the fused layer work
__global__ __launch_bounds__(512) void megaA(
    const float* __restrict__ x, const float* __restrict__ pos,
    const float* __restrict__ W11, const float* __restrict__ b11,
    const float* __restrict__ W12, const float* __restrict__ b12,
    int* __restrict__ samp1, float* __restrict__ pos2, float* __restrict__ h1full)
{
  // fps needs 18*NP1 + 4*NP2 + 32 + 128 = 82080 B
  __shared__ __align__(16) char smem[82112];
  if (blockIdx.x < BATCH) {
    const int b = blockIdx.x;
    fps_block<NP1, NP2>(smem, pos + (size_t)b * NP1 * 3, samp1 + b * NP2,
                        pos2 + (size_t)b * NP2 * 3);
  } else {
    const int id = blockIdx.x - BATCH;
    const int b = id >> 3;
    const int s = (id & 7) * 512 + threadIdx.x;
    fused_knn_pn<6, NP1, 1>(smem, pos + (size_t)b * NP1 * 3, x + (size_t)b * NP1,
                            nullptr, W11, b11, W12, b12,
                            h1full + (size_t)b * NP1 * 32, s);
  }
}

__global__ __launch_bounds__(512) void megaB(
    const float* __restrict__ pos2, const int* __restrict__ samp1,
    const float* __restrict__ h1full,
    const float* __restrict__ W21, const float* __restrict__ b21,
    const float* __restrict__ W22, const float* __restrict__ b22,
    int* __restrict__ samp2, float* __restrict__ pos3, float* __restrict__ h2full)
{
  // fps needs 18*NP2 + 4*NP3 + 32 + 128 = 41120 B ; fused needs 29312 B
  __shared__ __align__(16) char smem[41216];
  if (blockIdx.x < BATCH) {
    const int b = blockIdx.x;
    fps_block<NP2, NP3>(smem, pos2 + (size_t)b * NP2 * 3, samp2 + b * NP3,
                        pos3 + (size_t)b * NP3 * 3);
  } else {
    const int id = blockIdx.x - BATCH;
    const int b = id >> 2;
    const int s = (id & 3) * 512 + threadIdx.x;
    fused_knn_pn<4, NP2, 32>(smem, pos2 + (size_t)b * NP2 * 3,
                             h1full + (size_t)b * NP1 * 32, samp1 + b * NP2,
                             W21, b21, W22, b22,
                             h2full + (size_t)b * NP2 * 32, s);
  }
}

__global__ __launch_bounds__(512) void megaC(
    const float* __restrict__ pos3, const int* __restrict__ samp2,
    const float* __restrict__ h2full,
    const float* __restrict__ W31, const float* __restrict__ b31,
    const float* __restrict__ W32, const float* __restrict__ b32,
    float* __restrict__ h3full)
{
  __shared__ __align__(16) char smem[16 * 1024 + 67 * 8 * 16 + 32 * 8 * 16 + 256];
  const int b = blockIdx.x >> 1;
  const int s = (blockIdx.x & 1) * 512 + threadIdx.x;
  fused_knn_pn<3, NP3, 32>(smem, pos3 + (size_t)b * NP3 * 3,
                           h2full + (size_t)b * NP2 * 32, samp2 + b * NP3,
                           W31, b31, W32, b32,
                           h3full + (size_t)b * NP3 * 32, s);
}

// ---------------- global max pool over NP3 points + final linear 32->10
__global__ __launch_bounds__(256) void final_kernel(
    const float* __restrict__ h, const float* __restrict__ Wr,
    const float* __restrict__ br, float* __restrict__ out)
{
  __shared__ float red[8][32];
  __shared__ float g[32];
  const int b = blockIdx.x;
  const int c = threadIdx.x & 31, grp = threadIdx.x >> 5;
  const float* H = h + (size_t)b * NP3 * 32;
  float m = -__builtin_inff();
  for (int r = grp; r < NP3; r += 8) m = fmaxf(m, H[r * 32 + c]);
  red[grp][c] = m;
  __syncthreads();
  if (threadIdx.x < 32) {
    float v = red[0][c];
#pragma unroll
    for (int w = 1; w < 8; ++w) v = fmaxf(v, red[w][c]);
    g[c] = v;
  }
  __syncthreads();
  if (threadIdx.x < 10) {
    float v = br[threadIdx.x];
#pragma unroll
    for (int cc = 0; cc < 32; ++cc) v += g[cc] * Wr[cc * 10 + threadIdx.x];
    out[b * 10 + threadIdx.x] = v;
  }
}

extern "C" void kernel_launch(void* const* d_in, const int* in_sizes, int n_in,
                              void* d_out, int out_size, void* d_ws, size_t ws_size,
                              hipStream_t stream) {
  const float* x   = (const float*)d_in[0];
  const float* pos = (const float*)d_in[1];
  const float* W11 = (const float*)d_in[2];
  const float* b11 = (const float*)d_in[3];
  const float* W12 = (const float*)d_in[4];
  const float* b12 = (const float*)d_in[5];
  const float* W21 = (const float*)d_in[6];
  const float* b21 = (const float*)d_in[7];
  const float* W22 = (const float*)d_in[8];
  const float* b22 = (const float*)d_in[9];
  const float* W31 = (const float*)d_in[10];
  const float* b31 = (const float*)d_in[11];
  const float* W32 = (const float*)d_in[12];
  const float* b32 = (const float*)d_in[13];
  const float* Wr  = (const float*)d_in[14];
  const float* br  = (const float*)d_in[15];
  float* out = (float*)d_out;

  char* p = (char*)d_ws;
  auto alloc = [&](size_t bytes) {
    char* r = p; p += (bytes + 255) & ~(size_t)255; return r;
  };
  int*   samp1  = (int*)  alloc(sizeof(int)   * BATCH * NP2);
  float* pos2   = (float*)alloc(sizeof(float) * BATCH * NP2 * 3);
  int*   samp2  = (int*)  alloc(sizeof(int)   * BATCH * NP3);
  float* pos3   = (float*)alloc(sizeof(float) * BATCH * NP3 * 3);
  float* h1full = (float*)alloc(sizeof(float) * BATCH * NP1 * 32);  // 8 MB
  float* h2full = (float*)alloc(sizeof(float) * BATCH * NP2 * 32);  // 4 MB
  float* h3full = (float*)alloc(sizeof(float) * BATCH * NP3 * 32);  // 2 MB

  megaA<<<BATCH + BATCH * (NP1 / 512), 512, 0, stream>>>(     // 16 + 128
      x, pos, W11, b11, W12, b12, samp1, pos2, h1full);
  megaB<<<BATCH + BATCH * (NP2 / 512), 512, 0, stream>>>(     // 16 + 64
      pos2, samp1, h1full, W21, b21, W22, b22, samp2, pos3, h2full);
  megaC<<<BATCH * (NP3 / 512), 512, 0, stream>>>(             // 32
      pos3, samp2, h2full, W31, b31, W32, b32, h3full);
  final_kernel<<<BATCH, 256, 0, stream>>>(h3full, Wr, br, out);
}

// Round 8
// 2037.003 us; speedup vs baseline: 1.4568x; 1.4568x over previous
//
#include <hip/hip_runtime.h>

#define BATCH 16
#define NP1 4096
#define NP2 2048
#define NP3 1024

typedef float v2f __attribute__((ext_vector_type(2)));

// IEEE ops that the compiler may NOT contract/reorder — used for every distance
// that feeds a discrete decision (kNN membership, FPS argmax). Order matches the
// reference: norms (x*x+y*y)+z*z ; knn d = (ni+nj) - 2*dot ; fps d = (dx^2+dy^2)+dz^2.
__device__ __forceinline__ float f_add(float a, float b) { return __fadd_rn(a, b); }
__device__ __forceinline__ float f_mul(float a, float b) { return __fmul_rn(a, b); }
__device__ __forceinline__ float f_sub(float a, float b) { return __fsub_rn(a, b); }
__device__ __forceinline__ float sqnorm3(float x, float y, float z) {
  return f_add(f_add(f_mul(x, x), f_mul(y, y)), f_mul(z, z));
}

__device__ __forceinline__ unsigned long long u64max(unsigned long long a,
                                                     unsigned long long b) {
  return a > b ? a : b;
}

template<int CTRL, int RMASK>
__device__ __forceinline__ unsigned long long dpp_u64(unsigned long long k) {
  const int lo = __builtin_amdgcn_update_dpp(0, (int)(unsigned)k, CTRL, RMASK, 0xF, true);
  const int hi = __builtin_amdgcn_update_dpp(0, (int)(unsigned)(k >> 32), CTRL, RMASK, 0xF, true);
  return ((unsigned long long)(unsigned)hi << 32) | (unsigned)lo;
}

// Wave64 max-reduce of the packed key; lane 63 ends with the full wave max.
__device__ __forceinline__ unsigned long long wave_max_key(unsigned long long k) {
  k = u64max(k, dpp_u64<0x111, 0xF>(k));
  k = u64max(k, dpp_u64<0x112, 0xF>(k));
  k = u64max(k, dpp_u64<0x114, 0xF>(k));
  k = u64max(k, dpp_u64<0x118, 0xF>(k));
  k = u64max(k, dpp_u64<0x142, 0xA>(k));
  k = u64max(k, dpp_u64<0x143, 0xC>(k));
  return k;
}

// ---------------- FPS device block: exact replica of the reference scan.
// (See prior rounds: octant-sorted wave ranges + AABB cull; per-wave slot
// writes + broadcast tree read; LDS-only step loop.)
// NOTE: the SECOND fps of the network is provably the identity permutation
// (fps on the fps1-ordered subset re-picks rows 0,1,2,... bitwise — see
// round-8 journal proof), so this kernel is only ever instantiated for fps1.
template<int N, int M>
__device__ void fps_block(char* __restrict__ smem, const float* __restrict__ P,
                          int* __restrict__ samp, float* __restrict__ pos_out)
{
#pragma clang fp contract(off)
  constexpr int THREADS = 512;
  constexpr int E = N / THREADS;
  constexpr int P2 = E / 2;
  float4* pos4 = (float4*)smem;                                   // [N] by orig idx
  unsigned short* ord = (unsigned short*)(smem + 16 * N);         // [N]
  int* sampL = (int*)(smem + 18 * N);                             // [M]
  unsigned* cursor = (unsigned*)(smem + 18 * N + 4 * M);          // [8]
  unsigned long long* slots =
      (unsigned long long*)(smem + 18 * N + 4 * M + 32);          // [2][8]
  const int tid = threadIdx.x;
  const int lane = tid & 63, wv = tid >> 6;
  if (tid < 8) cursor[tid] = 0u;
  __syncthreads();
  int oct[E];
#pragma unroll
  for (int e = 0; e < E; ++e) {
    const int t = e * THREADS + tid;
    const float x = P[t * 3], y = P[t * 3 + 1], z = P[t * 3 + 2];
    pos4[t] = make_float4(x, y, z, 0.f);
    oct[e] = (x > 0.5f ? 1 : 0) | (y > 0.5f ? 2 : 0) | (z > 0.5f ? 4 : 0);
    atomicAdd(&cursor[oct[e]], 1u);
  }
  __syncthreads();
  if (tid == 0) {
    unsigned run = 0;
#pragma unroll
    for (int o = 0; o < 8; ++o) { const unsigned c = cursor[o]; cursor[o] = run; run += c; }
  }
  __syncthreads();
#pragma unroll
  for (int e = 0; e < E; ++e) {
    const unsigned d = atomicAdd(&cursor[oct[e]], 1u);
    ord[d] = (unsigned short)(e * THREADS + tid);
  }
  __syncthreads();
  const float4 p0 = pos4[0];
  const float x0 = p0.x, y0 = p0.y, z0 = p0.z;
  v2f X2[P2], Y2[P2], Z2[P2], MD2[P2];
  unsigned ILO[E];
  unsigned long long key = 0;
  float mnx = 1e30f, mny = 1e30f, mnz = 1e30f;
  float mxx = -1e30f, mxy = -1e30f, mxz = -1e30f;
  {
    const v2f x0v = {x0, x0}, y0v = {y0, y0}, z0v = {z0, z0};
#pragma unroll
    for (int p = 0; p < P2; ++p) {
      const int q0 = wv * (64 * E) + (2 * p) * 64 + lane;  // wave-contiguous sorted range
      const int o0 = ord[q0], o1 = ord[q0 + 64];
      const float4 a0 = pos4[o0], a1 = pos4[o1];
      X2[p] = (v2f){a0.x, a1.x}; Y2[p] = (v2f){a0.y, a1.y}; Z2[p] = (v2f){a0.z, a1.z};
      mnx = fminf(mnx, fminf(a0.x, a1.x)); mxx = fmaxf(mxx, fmaxf(a0.x, a1.x));
      mny = fminf(mny, fminf(a0.y, a1.y)); mxy = fmaxf(mxy, fmaxf(a0.y, a1.y));
      mnz = fminf(mnz, fminf(a0.z, a1.z)); mxz = fmaxf(mxz, fmaxf(a0.z, a1.z));
      const v2f dx = X2[p] - x0v, dy = Y2[p] - y0v, dz = Z2[p] - z0v;
      MD2[p] = (dx * dx + dy * dy) + dz * dz;
      ILO[2 * p]     = 0xFFFFFFFFu - (unsigned)o0;
      ILO[2 * p + 1] = 0xFFFFFFFFu - (unsigned)o1;
      const unsigned long long k0 =
          ((unsigned long long)__float_as_uint(MD2[p].x) << 32) | ILO[2 * p];
      const unsigned long long k1 =
          ((unsigned long long)__float_as_uint(MD2[p].y) << 32) | ILO[2 * p + 1];
      key = u64max(key, u64max(k0, k1));
    }
  }
#pragma unroll
  for (int off = 1; off < 64; off <<= 1) {
    mnx = fminf(mnx, __shfl_xor(mnx, off)); mxx = fmaxf(mxx, __shfl_xor(mxx, off));
    mny = fminf(mny, __shfl_xor(mny, off)); mxy = fmaxf(mxy, __shfl_xor(mxy, off));
    mnz = fminf(mnz, __shfl_xor(mnz, off)); mxz = fmaxf(mxz, __shfl_xor(mxz, off));
  }
  if (tid == 0) sampL[0] = 0;
  bool dirty = true;
  unsigned long long wkey = 0;
#pragma unroll 1
  for (int s = 1; s < M; ++s) {
    if (dirty) wkey = wave_max_key(key);   // dirty is wave-uniform: full-exec DPP
    const int pb = s & 1;
    if (lane == 63) slots[pb * 8 + wv] = wkey;
    __syncthreads();
    unsigned long long v0 = slots[pb * 8 + 0], v1 = slots[pb * 8 + 1];
    unsigned long long v2 = slots[pb * 8 + 2], v3 = slots[pb * 8 + 3];
    unsigned long long v4 = slots[pb * 8 + 4], v5 = slots[pb * 8 + 5];
    unsigned long long v6 = slots[pb * 8 + 6], v7 = slots[pb * 8 + 7];
    v0 = u64max(v0, v1); v2 = u64max(v2, v3); v4 = u64max(v4, v5); v6 = u64max(v6, v7);
    v0 = u64max(v0, v2); v4 = u64max(v4, v6);
    v0 = u64max(v0, v4);
    const int gi = (int)(0xFFFFFFFFu - (unsigned)v0);
    const float4 sp = pos4[gi];
    if (tid == 0) sampL[s] = gi;          // LDS only — no vmcnt in the loop
    // wave-uniform cull: lower bound on any rn-computed d(i,sample) in this wave
    const float mdx = fmaxf(fmaxf(f_sub(mnx, sp.x), f_sub(sp.x, mxx)), 0.f);
    const float mdy = fmaxf(fmaxf(f_sub(mny, sp.y), f_sub(sp.y, mxy)), 0.f);
    const float mdz = fmaxf(fmaxf(f_sub(mnz, sp.z), f_sub(sp.z, mxz)), 0.f);
    const float mind2 = sqnorm3(mdx, mdy, mdz);
    const unsigned wmhi = (unsigned)__builtin_amdgcn_readlane((int)(unsigned)(wkey >> 32), 63);
    const float wmaxf = __uint_as_float(wmhi);
    if (mind2 < wmaxf) {
      dirty = true;
      key = 0;
      const v2f sxv = {sp.x, sp.x}, syv = {sp.y, sp.y}, szv = {sp.z, sp.z};
#pragma unroll
      for (int p = 0; p < P2; ++p) {
        const v2f dx = X2[p] - sxv, dy = Y2[p] - syv, dz = Z2[p] - szv;
        const v2f d = (dx * dx + dy * dy) + dz * dz;
        MD2[p] = __builtin_elementwise_min(MD2[p], d);
        const unsigned long long k0 =
            ((unsigned long long)__float_as_uint(MD2[p].x) << 32) | ILO[2 * p];
        const unsigned long long k1 =
            ((unsigned long long)__float_as_uint(MD2[p].y) << 32) | ILO[2 * p + 1];
        key = u64max(key, u64max(k0, k1));
      }
    } else {
      dirty = false;
    }
  }
  __syncthreads();
  // bulk copy-out: indices + gathered positions, once
  for (int s2 = tid; s2 < M; s2 += THREADS) {
    const int g = sampL[s2];
    samp[s2] = g;
    const float4 sp2 = pos4[g];
    pos_out[3 * s2 + 0] = sp2.x;
    pos_out[3 * s2 + 1] = sp2.y;
    pos_out[3 * s2 + 2] = sp2.z;
  }
}

__device__ __forceinline__ float f4c(const float4& v, int c) {
  return c == 0 ? v.x : c == 1 ? v.y : c == 2 ? v.z : v.w;
}
__device__ __forceinline__ void fma4(float4& a, float v, const float4& w) {
  a.x += v * w.x; a.y += v * w.y; a.z += v * w.z; a.w += v * w.w;
}

// ---------------- PointNet edge MLP (2C+3 -> 32 -> relu -> 32, max over K, relu)
template<int K, int C>
__device__ void pn_compute(
    const float4* __restrict__ sW1, const float4* __restrict__ sW2,
    const float* __restrict__ sb1, const float* __restrict__ sb2,
    const float* __restrict__ P, const float* __restrict__ Hsrc,
    const int* __restrict__ hmap, int i, float xi, float yi, float zi,
    const int* kn, float* __restrict__ outrow)
{
  float4 abase[8];
#pragma unroll
  for (int o = 0; o < 8; ++o)
    abase[o] = make_float4(sb1[4 * o], sb1[4 * o + 1], sb1[4 * o + 2], sb1[4 * o + 3]);
  if constexpr (C == 1) {
    const float v = Hsrc[hmap ? hmap[i] : i];
#pragma unroll
    for (int o = 0; o < 8; ++o) fma4(abase[o], v, sW1[o]);
  } else {
    const int ri = hmap ? hmap[i] : i;
    const float4* Hi = (const float4*)(Hsrc + (size_t)ri * C);
#pragma unroll
    for (int c4 = 0; c4 < C / 4; ++c4) {
      const float4 hv = Hi[c4];
#pragma unroll
      for (int q = 0; q < 4; ++q) {
        const float v = f4c(hv, q);
#pragma unroll
        for (int o = 0; o < 8; ++o) fma4(abase[o], v, sW1[(4 * c4 + q) * 8 + o]);
      }
    }
  }
  float4 best[8];
#pragma unroll
  for (int o = 0; o < 8; ++o)
    best[o] = make_float4(-__builtin_inff(), -__builtin_inff(), -__builtin_inff(), -__builtin_inff());

  auto edge_pair = [&](int j0, int j1) {
    float4 a0[8], a1[8];
#pragma unroll
    for (int o = 0; o < 8; ++o) { a0[o] = abase[o]; a1[o] = abase[o]; }
    const float rx0 = P[j0 * 3] - xi, ry0 = P[j0 * 3 + 1] - yi, rz0 = P[j0 * 3 + 2] - zi;
    const float rx1 = P[j1 * 3] - xi, ry1 = P[j1 * 3 + 1] - yi, rz1 = P[j1 * 3 + 2] - zi;
    if constexpr (C == 1) {
      const float v0 = Hsrc[hmap ? hmap[j0] : j0], v1 = Hsrc[hmap ? hmap[j1] : j1];
#pragma unroll
      for (int o = 0; o < 8; ++o) {
        const float4 w = sW1[C * 8 + o];
        fma4(a0[o], v0, w); fma4(a1[o], v1, w);
      }
    } else {
      const int r0i = hmap ? hmap[j0] : j0, r1i = hmap ? hmap[j1] : j1;
      const float4* Hj0 = (const float4*)(Hsrc + (size_t)r0i * C);
      const float4* Hj1 = (const float4*)(Hsrc + (size_t)r1i * C);
#pragma unroll
      for (int c4 = 0; c4 < C / 4; ++c4) {
        const float4 h0 = Hj0[c4], h1 = Hj1[c4];
#pragma unroll
        for (int q = 0; q < 4; ++q) {
          const float v0 = f4c(h0, q), v1 = f4c(h1, q);
#pragma unroll
          for (int o = 0; o < 8; ++o) {
            const float4 w = sW1[(C + 4 * c4 + q) * 8 + o];
            fma4(a0[o], v0, w); fma4(a1[o], v1, w);
          }
        }
      }
    }
    const float r0[3] = {rx0, ry0, rz0}, r1[3] = {rx1, ry1, rz1};
#pragma unroll
    for (int r = 0; r < 3; ++r) {
#pragma unroll
      for (int o = 0; o < 8; ++o) {
        const float4 w = sW1[(2 * C + r) * 8 + o];
        fma4(a0[o], r0[r], w); fma4(a1[o], r1[r], w);
      }
    }
#pragma unroll
    for (int o = 0; o < 8; ++o) {
      a0[o].x = fmaxf(a0[o].x, 0.f); a0[o].y = fmaxf(a0[o].y, 0.f);
      a0[o].z = fmaxf(a0[o].z, 0.f); a0[o].w = fmaxf(a0[o].w, 0.f);
      a1[o].x = fmaxf(a1[o].x, 0.f); a1[o].y = fmaxf(a1[o].y, 0.f);
      a1[o].z = fmaxf(a1[o].z, 0.f); a1[o].w = fmaxf(a1[o].w, 0.f);
    }
#pragma unroll
    for (int hf = 0; hf < 2; ++hf) {
      float4 m0[4], m1[4];
#pragma unroll
      for (int o4 = 0; o4 < 4; ++o4) {
        const int c0 = 16 * hf + 4 * o4;
        m0[o4] = make_float4(sb2[c0], sb2[c0 + 1], sb2[c0 + 2], sb2[c0 + 3]);
        m1[o4] = m0[o4];
      }
#pragma unroll
      for (int c = 0; c < 32; ++c) {
        const float v0 = f4c(a0[c >> 2], c & 3), v1 = f4c(a1[c >> 2], c & 3);
#pragma unroll
        for (int o4 = 0; o4 < 4; ++o4) {
          const float4 w = sW2[c * 8 + hf * 4 + o4];
          fma4(m0[o4], v0, w); fma4(m1[o4], v1, w);
        }
      }
#pragma unroll
      for (int o4 = 0; o4 < 4; ++o4) {
        float4& bb = best[hf * 4 + o4];
        bb.x = fmaxf(bb.x, fmaxf(m0[o4].x, m1[o4].x));
        bb.y = fmaxf(bb.y, fmaxf(m0[o4].y, m1[o4].y));
        bb.z = fmaxf(bb.z, fmaxf(m0[o4].z, m1[o4].z));
        bb.w = fmaxf(bb.w, fmaxf(m0[o4].w, m1[o4].w));
      }
    }
  };

  auto edge_single = [&](int j0) {
    float4 a0[8];
#pragma unroll
    for (int o = 0; o < 8; ++o) a0[o] = abase[o];
    const float rx0 = P[j0 * 3] - xi, ry0 = P[j0 * 3 + 1] - yi, rz0 = P[j0 * 3 + 2] - zi;
    if constexpr (C == 1) {
      const float v0 = Hsrc[hmap ? hmap[j0] : j0];
#pragma unroll
      for (int o = 0; o < 8; ++o) fma4(a0[o], v0, sW1[C * 8 + o]);
    } else {
      const int r0i = hmap ? hmap[j0] : j0;
      const float4* Hj0 = (const float4*)(Hsrc + (size_t)r0i * C);
#pragma unroll
      for (int c4 = 0; c4 < C / 4; ++c4) {
        const float4 h0 = Hj0[c4];
#pragma unroll
        for (int q = 0; q < 4; ++q) {
          const float v0 = f4c(h0, q);
#pragma unroll
          for (int o = 0; o < 8; ++o) fma4(a0[o], v0, sW1[(C + 4 * c4 + q) * 8 + o]);
        }
      }
    }
    const float r0[3] = {rx0, ry0, rz0};
#pragma unroll
    for (int r = 0; r < 3; ++r)
#pragma unroll
      for (int o = 0; o < 8; ++o) fma4(a0[o], r0[r], sW1[(2 * C + r) * 8 + o]);
#pragma unroll
    for (int o = 0; o < 8; ++o) {
      a0[o].x = fmaxf(a0[o].x, 0.f); a0[o].y = fmaxf(a0[o].y, 0.f);
      a0[o].z = fmaxf(a0[o].z, 0.f); a0[o].w = fmaxf(a0[o].w, 0.f);
    }
#pragma unroll
    for (int hf = 0; hf < 2; ++hf) {
      float4 m0[4];
#pragma unroll
      for (int o4 = 0; o4 < 4; ++o4) {
        const int c0 = 16 * hf + 4 * o4;
        m0[o4] = make_float4(sb2[c0], sb2[c0 + 1], sb2[c0 + 2], sb2[c0 + 3]);
      }
#pragma unroll
      for (int c = 0; c < 32; ++c) {
        const float v0 = f4c(a0[c >> 2], c & 3);
#pragma unroll
        for (int o4 = 0; o4 < 4; ++o4) fma4(m0[o4], v0, sW2[c * 8 + hf * 4 + o4]);
      }
#pragma unroll
      for (int o4 = 0; o4 < 4; ++o4) {
        float4& bb = best[hf * 4 + o4];
        bb.x = fmaxf(bb.x, m0[o4].x); bb.y = fmaxf(bb.y, m0[o4].y);
        bb.z = fmaxf(bb.z, m0[o4].z); bb.w = fmaxf(bb.w, m0[o4].w);
      }
    }
  };

#pragma unroll
  for (int e = 0; e + 1 < K; e += 2) edge_pair(kn[e], kn[e + 1]);
  if constexpr (K & 1) edge_single(kn[K - 1]);

  float4* ho = (float4*)outrow;
#pragma unroll
  for (int o = 0; o < 8; ++o)
    ho[o] = make_float4(fmaxf(best[o].x, 0.0f), fmaxf(best[o].y, 0.0f),
                        fmaxf(best[o].z, 0.0f), fmaxf(best[o].w, 0.0f));
}

// ---------------- fused kNN + PN layer, one query per thread.
template<int K, int NC, int C, int THREADS>
__device__ void fused_knn_pn(char* __restrict__ smem,
    const float* __restrict__ P, const float* __restrict__ Hsrc,
    const int* __restrict__ hmap,
    const float* __restrict__ W1, const float* __restrict__ b1,
    const float* __restrict__ W2, const float* __restrict__ b2,
    float* __restrict__ hout, int s)
{
  constexpr int CIN = 2 * C + 3;
  float4* tile = (float4*)smem;                       // [1024]
  float4* sW1 = (float4*)(smem + 16 * 1024);          // [CIN*8]
  float4* sW2 = sW1 + CIN * 8;                        // [32*8]
  float* sb1 = (float*)(sW2 + 32 * 8);
  float* sb2 = sb1 + 32;
  const int tid = threadIdx.x;
  for (int t = tid; t < CIN * 8; t += THREADS) sW1[t] = ((const float4*)W1)[t];
  for (int t = tid; t < 32 * 8; t += THREADS) sW2[t] = ((const float4*)W2)[t];
  if (tid < 32) { sb1[tid] = b1[tid]; sb2[tid] = b2[tid]; }

  const float xi = P[s * 3], yi = P[s * 3 + 1], zi = P[s * 3 + 2];
  const float ni = sqnorm3(xi, yi, zi);
  float bd[K]; int bj[K];
#pragma unroll
  for (int t = 0; t < K; ++t) { bd[t] = __builtin_inff(); bj[t] = 0; }
  for (int base = 0; base < NC; base += 1024) {
    __syncthreads();
    for (int t = tid; t < 1024; t += THREADS) {
      const float* q = P + (size_t)(base + t) * 3;
      const float x = q[0], y = q[1], z = q[2];
      tile[t] = make_float4(x, y, z, sqnorm3(x, y, z));
    }
    __syncthreads();
#pragma unroll 2
    for (int t = 0; t < 1024; ++t) {
      const float4 q = tile[t];
      const float dot = f_add(f_add(f_mul(xi, q.x), f_mul(yi, q.y)), f_mul(zi, q.z));
      const float d = f_sub(f_add(ni, q.w), f_mul(2.0f, dot));
      if (d < bd[K - 1]) {          // strict < keeps earlier index on ties
        bd[K - 1] = d; bj[K - 1] = base + t;
#pragma unroll
        for (int r = K - 1; r > 0; --r) {
          if (bd[r] < bd[r - 1]) {
            float td = bd[r]; bd[r] = bd[r - 1]; bd[r - 1] = td;
            int   tj = bj[r]; bj[r] = bj[r - 1]; bj[r - 1] = tj;
          } else break;
        }
      }
    }
  }
  pn_compute<K, C>(sW1, sW2, sb1, sb2, P, Hsrc, hmap, s, xi, yi, zi, bj,
                   hout + (size_t)s * 32);
}

// ---------------- megaA: fps1 rides alongside fused knn1+pn1 (all 4096 queries)
__global__ __launch_bounds__(512) void megaA(
    const float* __restrict__ x, const float* __restrict__ pos,
    const float* __restrict__ W11, const float* __restrict__ b11,
    const float* __restrict__ W12, const float* __restrict__ b12,
    int* __restrict__ samp1, float* __restrict__ pos2, float* __restrict__ h1full)
{
  // fps needs 18*NP1 + 4*NP2 + 32 + 128 = 82080 B
  __shared__ __align__(16) char smem[82112];
  if (blockIdx.x < BATCH) {
    const int b = blockIdx.x;
    fps_block<NP1, NP2>(smem, pos + (size_t)b * NP1 * 3, samp1 + b * NP2,
                        pos2 + (size_t)b * NP2 * 3);
  } else {
    const int id = blockIdx.x - BATCH;
    const int b = id >> 3;
    const int s = (id & 7) * 512 + threadIdx.x;
    fused_knn_pn<6, NP1, 1, 512>(smem, pos + (size_t)b * NP1 * 3, x + (size_t)b * NP1,
                                 nullptr, W11, b11, W12, b12,
                                 h1full + (size_t)b * NP1 * 32, s);
  }
}

// ---------------- megaB: layer 2, NO fps (fps2 == identity — proof in journal).
// Queries = pos2 rows 0..1023 only (the rows layer-3 consumes); candidates =
// all 2048 pos2 rows; h via samp1 into the full layer-1 output.
__global__ __launch_bounds__(256) void megaB(
    const float* __restrict__ pos2, const int* __restrict__ samp1,
    const float* __restrict__ h1full,
    const float* __restrict__ W21, const float* __restrict__ b21,
    const float* __restrict__ W22, const float* __restrict__ b22,
    float* __restrict__ h2out)
{
  __shared__ __align__(16) char smem[16 * 1024 + 67 * 8 * 16 + 32 * 8 * 16 + 256];
  const int b = blockIdx.x >> 2;
  const int s = (blockIdx.x & 3) * 256 + threadIdx.x;
  fused_knn_pn<4, NP2, 32, 256>(smem, pos2 + (size_t)b * NP2 * 3,
                                h1full + (size_t)b * NP1 * 32, samp1 + b * NP2,
                                W21, b21, W22, b22,
                                h2out + (size_t)b * NP3 * 32, s);
}

// ---------------- megaC: layer 3 on pos3 = pos2 rows 0..1023, h3 = h2out rows.
__global__ __launch_bounds__(256) void megaC(
    const float* __restrict__ pos2, const float* __restrict__ h2out,
    const float* __restrict__ W31, const float* __restrict__ b31,
    const float* __restrict__ W32, const float* __restrict__ b32,
    float* __restrict__ h3full)
{
  __shared__ __align__(16) char smem[16 * 1024 + 67 * 8 * 16 + 32 * 8 * 16 + 256];
  const int b = blockIdx.x >> 2;
  const int s = (blockIdx.x & 3) * 256 + threadIdx.x;
  // candidates = first 1024 rows of pos2 (contiguous prefix of the row-major array)
  fused_knn_pn<3, NP3, 32, 256>(smem, pos2 + (size_t)b * NP2 * 3,
                                h2out + (size_t)b * NP3 * 32, nullptr,
                                W31, b31, W32, b32,
                                h3full + (size_t)b * NP3 * 32, s);
}

// ---------------- global max pool over NP3 points + final linear 32->10
__global__ __launch_bounds__(256) void final_kernel(
    const float* __restrict__ h, const float* __restrict__ Wr,
    const float* __restrict__ br, float* __restrict__ out)
{
  __shared__ float red[8][32];
  __shared__ float g[32];
  const int b = blockIdx.x;
  const int c = threadIdx.x & 31, grp = threadIdx.x >> 5;
  const float* H = h + (size_t)b * NP3 * 32;
  float m = -__builtin_inff();
  for (int r = grp; r < NP3; r += 8) m = fmaxf(m, H[r * 32 + c]);
  red[grp][c] = m;
  __syncthreads();
  if (threadIdx.x < 32) {
    float v = red[0][c];
#pragma unroll
    for (int w = 1; w < 8; ++w) v = fmaxf(v, red[w][c]);
    g[c] = v;
  }
  __syncthreads();
  if (threadIdx.x < 10) {
    float v = br[threadIdx.x];
#pragma unroll
    for (int cc = 0; cc < 32; ++cc) v += g[cc] * Wr[cc * 10 + threadIdx.x];
    out[b * 10 + threadIdx.x] = v;
  }
}

extern "C" void kernel_launch(void* const* d_in, const int* in_sizes, int n_in,
                              void* d_out, int out_size, void* d_ws, size_t ws_size,
                              hipStream_t stream) {
  const float* x   = (const float*)d_in[0];
  const float* pos = (const float*)d_in[1];
  const float* W11 = (const float*)d_in[2];
  const float* b11 = (const float*)d_in[3];
  const float* W12 = (const float*)d_in[4];
  const float* b12 = (const float*)d_in[5];
  const float* W21 = (const float*)d_in[6];
  const float* b21 = (const float*)d_in[7];
  const float* W22 = (const float*)d_in[8];
  const float* b22 = (const float*)d_in[9];
  const float* W31 = (const float*)d_in[10];
  const float* b31 = (const float*)d_in[11];
  const float* W32 = (const float*)d_in[12];
  const float* b32 = (const float*)d_in[13];
  const float* Wr  = (const float*)d_in[14];
  const float* br  = (const float*)d_in[15];
  float* out = (float*)d_out;

  char* p = (char*)d_ws;
  auto alloc = [&](size_t bytes) {
    char* r = p; p += (bytes + 255) & ~(size_t)255; return r;
  };
  int*   samp1  = (int*)  alloc(sizeof(int)   * BATCH * NP2);
  float* pos2   = (float*)alloc(sizeof(float) * BATCH * NP2 * 3);
  float* h1full = (float*)alloc(sizeof(float) * BATCH * NP1 * 32);  // 8 MB
  float* h2out  = (float*)alloc(sizeof(float) * BATCH * NP3 * 32);  // 2 MB
  float* h3full = (float*)alloc(sizeof(float) * BATCH * NP3 * 32);  // 2 MB

  megaA<<<BATCH + BATCH * (NP1 / 512), 512, 0, stream>>>(     // 16 + 128
      x, pos, W11, b11, W12, b12, samp1, pos2, h1full);
  megaB<<<BATCH * 4, 256, 0, stream>>>(                       // 64
      pos2, samp1, h1full, W21, b21, W22, b22, h2out);
  megaC<<<BATCH * 4, 256, 0, stream>>>(                       // 64
      pos2, h2out, W31, b31, W32, b32, h3full);
  final_kernel<<<BATCH, 256, 0, stream>>>(h3full, Wr, br, out);
}